// Round 3
// baseline (72.489 us; speedup 1.0000x reference)
//
#include <hip/hip_runtime.h>
#include <hip/hip_fp16.h>

typedef _Float16 half8 __attribute__((ext_vector_type(8)));
typedef float floatx4 __attribute__((ext_vector_type(4)));

#define KH 256            // H (inner / K dim)
#define NN 1024           // N heads
#define BM 64             // b-rows per block (4 waves x 16)
#define NSPLIT 2          // split N across blockIdx.y for occupancy
#define NG (NN / 16)      // 64 16-col groups
#define GPB (NG / NSPLIT) // 32 groups per block

// ---------------- pack kernel: W fp32 -> f16, MFMA-fragment order ----------
// packed f16 index: ((g*8 + ks)*64 + lane)*8 + j
//   where n = g*16 + (lane&15), k = ks*32 + (lane>>4)*8 + j
__global__ __launch_bounds__(256)
void pack_w(const float* __restrict__ W, _Float16* __restrict__ P) {
    const int u  = blockIdx.x * 256 + threadIdx.x;   // 32768 threads total
    const int g  = u >> 9;
    const int ks = (u >> 6) & 7;
    const int l  = u & 63;
    const int n  = g * 16 + (l & 15);
    const int kb = ks * 32 + ((l >> 4) << 3);
    const float* src = W + (size_t)n * KH + kb;
    floatx4 lo = *(const floatx4*)src;
    floatx4 hi = *(const floatx4*)(src + 4);
    half8 h;
    h[0] = (_Float16)lo[0]; h[1] = (_Float16)lo[1];
    h[2] = (_Float16)lo[2]; h[3] = (_Float16)lo[3];
    h[4] = (_Float16)hi[0]; h[5] = (_Float16)hi[1];
    h[6] = (_Float16)hi[2]; h[7] = (_Float16)hi[3];
    *(half8*)(P + (size_t)u * 8) = h;                // fully coalesced 16B/lane
}

// ---------------- main kernel: no LDS, no memory barriers ------------------
__global__ __launch_bounds__(256, 4)
void lfh_main(const float* __restrict__ x, const _Float16* __restrict__ P,
              const float* __restrict__ bias, float* __restrict__ out) {
    const int t   = threadIdx.x;
    const int w   = t >> 6;
    const int l   = t & 63;
    const int l15 = l & 15;
    const int lq  = l >> 4;
    const int brow = blockIdx.x * BM + w * 16 + l15;
    const int g0   = blockIdx.y * GPB;

    // ---- A fragments (x rows), fp32 -> f16, kept in registers -------------
    half8 afrag[8];
    {
        const float* xr = x + (size_t)brow * KH;
        #pragma unroll
        for (int ks = 0; ks < 8; ++ks) {
            const int kb = ks * 32 + lq * 8;
            floatx4 lo = *(const floatx4*)(xr + kb);
            floatx4 hi = *(const floatx4*)(xr + kb + 4);
            half8 f;
            f[0] = (_Float16)lo[0]; f[1] = (_Float16)lo[1];
            f[2] = (_Float16)lo[2]; f[3] = (_Float16)lo[3];
            f[4] = (_Float16)hi[0]; f[5] = (_Float16)hi[1];
            f[6] = (_Float16)hi[2]; f[7] = (_Float16)hi[3];
            afrag[ks] = f;
        }
    }

    float* orow = out + (size_t)brow * NN;
    const _Float16* Pl = P + (size_t)l * 8;   // lane's slot within each frag row

    for (int gg = 0; gg < GPB; gg += 4) {     // 8 supertiles of 4 groups
        #pragma unroll
        for (int nf = 0; nf < 4; ++nf) {
            const int g = g0 + gg + nf;
            // fragment base for (g, ks): P + g*4096 + ks*512 + l*8 (f16 elems)
            const _Float16* fb = Pl + (size_t)g * 4096;
            floatx4 acc = (floatx4)0.0f;
            #pragma unroll
            for (int ks = 0; ks < 8; ++ks) {
                half8 wf = *(const half8*)(fb + ks * 512);
                // swapped operands: D col = b-row (lane&15), D row = n_local
                acc = __builtin_amdgcn_mfma_f32_16x16x32_f16(wf, afrag[ks], acc, 0, 0, 0);
            }
            const int nb = g * 16 + lq * 4;
            floatx4 bv = *(const floatx4*)(bias + nb);
            floatx4 r;
            #pragma unroll
            for (int j = 0; j < 4; ++j) {
                const float z = acc[j] + bv[j];
                r[j] = __builtin_amdgcn_rcpf(1.0f + __expf(-z));
            }
            __builtin_nontemporal_store(r, (floatx4*)(orow + nb));
        }
        // raw rendezvous only (no waitcnt, no store drain): keeps the block's
        // 4 waves phase-locked so their W-fragment stream overlaps in L1
        __builtin_amdgcn_s_barrier();
    }
}

extern "C" void kernel_launch(void* const* d_in, const int* in_sizes, int n_in,
                              void* d_out, int out_size, void* d_ws, size_t ws_size,
                              hipStream_t stream) {
    const float* x = (const float*)d_in[0];
    const float* W = (const float*)d_in[1];
    const float* b = (const float*)d_in[2];
    float* out = (float*)d_out;
    _Float16* P = (_Float16*)d_ws;            // 512 KB packed f16 W

    pack_w<<<dim3(128), dim3(256), 0, stream>>>(W, P);

    const int Btot = in_sizes[0] / KH;        // 32768
    lfh_main<<<dim3(Btot / BM, NSPLIT), dim3(256), 0, stream>>>(x, P, b, out);
}